// Round 5
// baseline (4135.081 us; speedup 1.0000x reference)
//
#include <hip/hip_runtime.h>
#include <math.h>

#define CCH 32        // channels
#define NCH 224       // 7*C radial outputs
#define NIV 33        // PWL intervals
#define HRAD 32
#define ET 16         // nodes per epi block-iter

// ---------------- CSR build ----------------

__global__ void hist_kernel(const int* __restrict__ dst, int* __restrict__ counts, int E) {
  int e = blockIdx.x * 256 + threadIdx.x;
  if (e < E) atomicAdd(&counts[dst[e]], 1);
}

__global__ void scan1_kernel(const int* __restrict__ counts, int* __restrict__ offs,
                             int* __restrict__ bsums, int n) {
  __shared__ int sd[1024];
  int t = threadIdx.x;
  int i = blockIdx.x * 1024 + t;
  int v = (i < n) ? counts[i] : 0;
  sd[t] = v;
  __syncthreads();
  for (int o = 1; o < 1024; o <<= 1) {
    int add = (t >= o) ? sd[t - o] : 0;
    __syncthreads();
    sd[t] += add;
    __syncthreads();
  }
  if (i < n) offs[i] = sd[t] - v;          // block-local exclusive
  if (t == 1023) bsums[blockIdx.x] = sd[1023];
}

__global__ void scan2_kernel(int* bsums, int nb) {
  if (threadIdx.x == 0 && blockIdx.x == 0) {
    int acc = 0;
    for (int i = 0; i < nb; i++) { int v = bsums[i]; bsums[i] = acc; acc += v; }
  }
}

__global__ void scan3_kernel(int* __restrict__ offs, const int* __restrict__ bsums,
                             int* __restrict__ cursor, int n, int E) {
  int i = blockIdx.x * 256 + threadIdx.x;
  if (i < n) {
    int v = offs[i] + bsums[i >> 10];
    offs[i] = v;
    cursor[i] = v;
  } else if (i == n) {
    offs[n] = E;
  }
}

__global__ void scatter_kernel(const float* __restrict__ pos, const int* __restrict__ src,
                               const int* __restrict__ dst, int* __restrict__ cursor,
                               int* __restrict__ esrcS, float4* __restrict__ egeoS, int E) {
  int e = blockIdx.x * 256 + threadIdx.x;
  if (e >= E) return;
  int s = src[e], d = dst[e];
  float rx = pos[d * 3 + 0] - pos[s * 3 + 0];
  float ry = pos[d * 3 + 1] - pos[s * 3 + 1];
  float rz = pos[d * 3 + 2] - pos[s * 3 + 2];
  float rl = sqrtf(rx * rx + ry * ry + rz * rz);
  float inv = 1.0f / (rl + 1e-6f);
  int p = atomicAdd(&cursor[d], 1);
  esrcS[p] = s;
  egeoS[p] = make_float4(rx * inv, ry * inv, rz * inv, rl);
}

// ---------------- exact piecewise-linear collapse of the radial MLP ----------------

__global__ void pwl_build_kernel(const float* __restrict__ W1, const float* __restrict__ b1,
                                 const float* __restrict__ W2, const float* __restrict__ b2,
                                 float2* __restrict__ coef, float* __restrict__ tks) {
  int l = blockIdx.x;
  int tid = threadIdx.x;
  const float* w1 = W1 + l * HRAD;
  const float* bb1 = b1 + l * HRAD;
  const float* w2 = W2 + l * HRAD * NCH;
  const float* bb2 = b2 + l * NCH;
  __shared__ float a_s[HRAD], b_s[HRAD], t_s[HRAD], t_sorted[HRAD];
  if (tid < HRAD) {
    float a = w1[tid], b = bb1[tid];
    a_s[tid] = a; b_s[tid] = b;
    t_s[tid] = (a != 0.0f) ? (-b / a) : 1e30f;
  }
  __syncthreads();
  if (tid < HRAD) {
    float tj = t_s[tid];
    int rank = 0;
    for (int k = 0; k < HRAD; k++) {
      float tk = t_s[k];
      rank += (tk < tj) || (tk == tj && k < tid);
    }
    t_sorted[rank] = tj;
    tks[l * HRAD + tid] = tj;   // UNSORTED kinks (count-of-smaller is order-free)
  }
  __syncthreads();
  for (int idx = tid; idx < NIV * NCH; idx += blockDim.x) {
    int iv = idx / NCH;
    int k = idx - iv * NCH;
    double lo = (iv == 0) ? (double)t_sorted[0] - 1.0 : (double)t_sorted[iv - 1];
    double hi = (iv == NIV - 1) ? (double)t_sorted[HRAD - 1] + 1.0 : (double)t_sorted[iv];
    double rm = 0.5 * (lo + hi);
    if (iv == 0) rm = (double)t_sorted[0] - 1.0;
    if (iv == NIV - 1) rm = (double)t_sorted[HRAD - 1] + 1.0;
    float alpha = bb2[k];
    float beta = 0.0f;
    for (int j = 0; j < HRAD; j++) {
      if ((double)a_s[j] * rm + (double)b_s[j] > 0.0) {
        float w = w2[j * NCH + k];
        alpha = fmaf(w, b_s[j], alpha);
        beta = fmaf(w, a_s[j], beta);
      }
    }
    coef[l * (NIV * NCH) + idx] = make_float2(alpha, beta);
  }
}

// ---------------- initial pack (f0,f1 -> float4 rows) + q for layer 0 ----------------

__global__ __launch_bounds__(512) void pack_kernel(
    const float* __restrict__ f0, const float* __restrict__ f1,
    const float* __restrict__ Wq0, float scale0,
    float4* __restrict__ fpk, float* __restrict__ qbuf, int n) {
  __shared__ float sWq[1024];
  __shared__ float sF0[ET * 32];
  int tid = threadIdx.x;
  for (int i = tid; i < 1024; i += 512) sWq[i] = Wq0[i];
  __syncthreads();
  int nl = tid >> 5, c = tid & 31;
  for (int base = blockIdx.x * ET; base < n; base += gridDim.x * ET) {
    int node = base + nl;
    float v0 = 0.f, x = 0.f, y = 0.f, z = 0.f;
    if (node < n) {
      v0 = f0[node * 32 + c];
      int b = (node * 32 + c) * 3;
      x = f1[b]; y = f1[b + 1]; z = f1[b + 2];
      fpk[node * 32 + c] = make_float4(v0, x, y, z);
    }
    sF0[nl * 32 + c] = v0;
    __syncthreads();
    if (node < n) {
      float q = 0.f;
#pragma unroll
      for (int k = 0; k < 32; k++) q = fmaf(sF0[nl * 32 + k], sWq[k * 32 + c], q);
      qbuf[node * 32 + c] = q * scale0;
    }
    __syncthreads();
  }
}

// ---------------- per-node attention (softmax-weighted aggregation only) ----------------
// One wave per node. lane = c + 32*half. Each half runs TWO independent edge
// chains (stride 4) with separate online-softmax states -> 4 gathers in flight
// per wave, no register rotation (each chain is an R2-style depth-1 prefetch).
// Chains merge in-register; halves merge via shfl_xor(32).

__global__ __launch_bounds__(1024, 8) void node_kernel(
    const float4* __restrict__ fpk, const float* __restrict__ qbuf,
    float4* __restrict__ Opk,
    const int* __restrict__ esrcS, const float4* __restrict__ egeoS,
    const int* __restrict__ offs,
    const float2* __restrict__ coefG, const float* __restrict__ tkG,
    int ch, int n) {
  __shared__ float2 sCoef[NIV * NCH];   // 59136 B
  __shared__ float sTk[CCH];
  int tid = threadIdx.x;
  for (int i = tid; i < NIV * NCH; i += 1024) sCoef[i] = coefG[i];
  if (tid < CCH) sTk[tid] = tkG[tid];
  __syncthreads();

  int lane = tid & 63;
  int wid = tid >> 6;
  int c = lane & 31;
  int half = lane >> 5;
  float tk_c = sTk[c];
  unsigned long long hmask = half ? 0xFFFFFFFF00000000ull : 0xFFFFFFFFull;
  int hsh = half ? 32 : 0;

  for (int node = blockIdx.x * 16 + wid; node < n; node += gridDim.x * 16) {
    float qs = qbuf[node * 32 + c];   // pre-scaled q
    int start = offs[node], end = offs[node + 1];
    float m0 = -INFINITY, z0 = 0.0f, a00 = 0.f, a010 = 0.f, a011 = 0.f, a012 = 0.f;
    float m1 = -INFINITY, z1 = 0.0f, a10 = 0.f, a110 = 0.f, a111 = 0.f, a112 = 0.f;

    int j = start + half;
    // chain0: edges j, j+4, ... ; chain1: edges j+2, j+6, ...
    int s0B = 0, s1B = 0;
    float4 g0A = make_float4(0, 0, 0, 0), g0B = make_float4(0, 0, 0, 0);
    float4 g1A = make_float4(0, 0, 0, 0), g1B = make_float4(0, 0, 0, 0);
    float4 F0A = make_float4(0, 0, 0, 0), F1A = make_float4(0, 0, 0, 0);
    if (j < end)     { int s = esrcS[j];     g0A = egeoS[j];     F0A = fpk[s * 32 + c]; }
    if (j + 2 < end) { int s = esrcS[j + 2]; g1A = egeoS[j + 2]; F1A = fpk[s * 32 + c]; }
    if (j + 4 < end) { s0B = esrcS[j + 4]; g0B = egeoS[j + 4]; }
    if (j + 6 < end) { s1B = esrcS[j + 6]; g1B = egeoS[j + 6]; }

    while (j < end) {
      // ---- chain0: edge j ----
      {
        float4 g = g0A;
        float4 F = F0A;
        if (j + 4 < end) {
          F0A = fpk[s0B * 32 + c];
          g0A = g0B;
          if (j + 8 < end) { s0B = esrcS[j + 8]; g0B = egeoS[j + 8]; }
        }
        unsigned long long msk = __ballot(g.w > tk_c);
        int iv = (int)__popcll(msk & hmask) ;
        iv = half ? (int)__popcll(msk >> 32) : (int)__popcll(msk & 0xFFFFFFFFull);
        const float2* cf = sCoef + iv * NCH + c;
        float r = g.w;
        float2 q0 = cf[0],   q1 = cf[32],  q2 = cf[64], q3 = cf[96];
        float2 q4 = cf[128], q5 = cf[160], q6 = cf[192];
        float rk00 = fmaf(q0.y, r, q0.x), rk10 = fmaf(q1.y, r, q1.x);
        float rv00 = fmaf(q2.y, r, q2.x), rv10 = fmaf(q3.y, r, q3.x);
        float rv11 = fmaf(q4.y, r, q4.x), rv01 = fmaf(q5.y, r, q5.x);
        float rv11b = fmaf(q6.y, r, q6.x);
        float dot1 = fmaf(F.y, g.x, fmaf(F.z, g.y, F.w * g.z));
        float k0 = fmaf(rk00, F.x, rk10 * dot1);
        float t = qs * k0;
        for (int o = 1; o < ch; o <<= 1) t += __shfl_xor(t, o, 64);
        float mn = fmaxf(m0, t);
        float a = __expf(m0 - mn);
        float p = __expf(t - mn);
        m0 = mn;
        z0 = fmaf(z0, a, p);
        float v0 = fmaf(rv00, F.x, rv10 * dot1);
        float sg = fmaf(rv01, F.x, rv11b * dot1);
        a00  = fmaf(a00,  a, p * v0);
        a010 = fmaf(a010, a, p * fmaf(rv11, F.y, sg * g.x));
        a011 = fmaf(a011, a, p * fmaf(rv11, F.z, sg * g.y));
        a012 = fmaf(a012, a, p * fmaf(rv11, F.w, sg * g.z));
      }
      // ---- chain1: edge j+2 ----
      if (j + 2 < end) {
        float4 g = g1A;
        float4 F = F1A;
        if (j + 6 < end) {
          F1A = fpk[s1B * 32 + c];
          g1A = g1B;
          if (j + 10 < end) { s1B = esrcS[j + 10]; g1B = egeoS[j + 10]; }
        }
        unsigned long long msk = __ballot(g.w > tk_c);
        int iv = half ? (int)__popcll(msk >> 32) : (int)__popcll(msk & 0xFFFFFFFFull);
        const float2* cf = sCoef + iv * NCH + c;
        float r = g.w;
        float2 q0 = cf[0],   q1 = cf[32],  q2 = cf[64], q3 = cf[96];
        float2 q4 = cf[128], q5 = cf[160], q6 = cf[192];
        float rk00 = fmaf(q0.y, r, q0.x), rk10 = fmaf(q1.y, r, q1.x);
        float rv00 = fmaf(q2.y, r, q2.x), rv10 = fmaf(q3.y, r, q3.x);
        float rv11 = fmaf(q4.y, r, q4.x), rv01 = fmaf(q5.y, r, q5.x);
        float rv11b = fmaf(q6.y, r, q6.x);
        float dot1 = fmaf(F.y, g.x, fmaf(F.z, g.y, F.w * g.z));
        float k0 = fmaf(rk00, F.x, rk10 * dot1);
        float t = qs * k0;
        for (int o = 1; o < ch; o <<= 1) t += __shfl_xor(t, o, 64);
        float mn = fmaxf(m1, t);
        float a = __expf(m1 - mn);
        float p = __expf(t - mn);
        m1 = mn;
        z1 = fmaf(z1, a, p);
        float v0 = fmaf(rv00, F.x, rv10 * dot1);
        float sg = fmaf(rv01, F.x, rv11b * dot1);
        a10  = fmaf(a10,  a, p * v0);
        a110 = fmaf(a110, a, p * fmaf(rv11, F.y, sg * g.x));
        a111 = fmaf(a111, a, p * fmaf(rv11, F.z, sg * g.y));
        a112 = fmaf(a112, a, p * fmaf(rv11, F.w, sg * g.z));
      }
      j += 4;
    }

    // ---- merge chain0/chain1 (in-register) ----
    float m = fmaxf(m0, m1);
    float c0 = 0.f, c1 = 0.f;
    if (m > -INFINITY) { c0 = __expf(m0 - m); c1 = __expf(m1 - m); }
    float z   = z0 * c0 + z1 * c1;
    float o0  = a00 * c0 + a10 * c1;
    float o10 = a010 * c0 + a110 * c1;
    float o11 = a011 * c0 + a111 * c1;
    float o12 = a012 * c0 + a112 * c1;

    // ---- merge the two half-wave softmax states ----
    float mo  = __shfl_xor(m, 32, 64);
    float zo  = __shfl_xor(z, 32, 64);
    float p0  = __shfl_xor(o0, 32, 64);
    float p10 = __shfl_xor(o10, 32, 64);
    float p11 = __shfl_xor(o11, 32, 64);
    float p12 = __shfl_xor(o12, 32, 64);
    float mf = fmaxf(m, mo);
    float aA = 0.0f, aB = 0.0f;
    if (mf > -INFINITY) { aA = __expf(m - mf); aB = __expf(mo - mf); }
    float zf = z * aA + zo * aB;
    float inv = 1.0f / (zf + 1e-6f);
    if (!half) {
      Opk[node * 32 + c] = make_float4(
          (o0 * aA + p0 * aB) * inv,
          (o10 * aA + p10 * aB) * inv,
          (o11 * aA + p11 * aB) * inv,
          (o12 * aA + p12 * aB) * inv);
    }
  }
}

// ---------------- dense epilogue: out = O@Wo + f@Ws, NL, next-layer q ----------------

__global__ __launch_bounds__(512) void epi_kernel(
    const float4* __restrict__ Opk, float4* __restrict__ fpk,
    const float* __restrict__ Wo0G, const float* __restrict__ Ws0G,
    const float* __restrict__ Wo1G, const float* __restrict__ Ws1G,
    const float* __restrict__ bgG,
    const float* __restrict__ WqN, float* __restrict__ qbuf, float scaleN,
    float* __restrict__ out0, float* __restrict__ out1,
    int mode, int n) {
  __shared__ float4 sW[32 * 32];     // (wo0, ws0, wo1, ws1) 16 KB
  __shared__ float  sWq[32 * 32];    // 4 KB
  __shared__ float4 sO[ET * 32];     // 8 KB
  __shared__ float4 sF[ET * 32];     // 8 KB
  __shared__ float  sF0[ET * 32];    // 2 KB
  int tid = threadIdx.x;
  for (int i = tid; i < 1024; i += 512) {
    sW[i] = make_float4(Wo0G[i], Ws0G[i], Wo1G[i], Ws1G[i]);
    if (mode == 0) sWq[i] = WqN[i];
  }
  __syncthreads();
  int nl = tid >> 5;
  int c  = tid & 31;
  for (int base = blockIdx.x * ET; base < n; base += gridDim.x * ET) {
    int node = base + nl;
    bool valid = node < n;
    if (valid) {
      sO[tid] = Opk[node * 32 + c];
      sF[tid] = fpk[node * 32 + c];
    }
    __syncthreads();
    float a0 = 0.f, ax = 0.f, ay = 0.f, az = 0.f;
#pragma unroll
    for (int k = 0; k < 32; k++) {
      float4 O = sO[nl * 32 + k];
      float4 F = sF[nl * 32 + k];
      float4 w = sW[k * 32 + c];
      a0 = fmaf(O.x, w.x, fmaf(F.x, w.y, a0));
      ax = fmaf(O.y, w.z, fmaf(F.y, w.w, ax));
      ay = fmaf(O.z, w.z, fmaf(F.z, w.w, ay));
      az = fmaf(O.w, w.z, fmaf(F.w, w.w, az));
    }
    if (mode == 0) {
      float f0n = fmaxf(a0, 0.f);
      float n1 = sqrtf(fmaf(ax, ax, fmaf(ay, ay, az * az)));
      float gate = fmaxf(n1 + bgG[c], 0.f) / (n1 + 1e-6f);
      if (valid) fpk[node * 32 + c] = make_float4(f0n, ax * gate, ay * gate, az * gate);
      sF0[nl * 32 + c] = f0n;
      __syncthreads();
      if (valid) {
        float q = 0.f;
#pragma unroll
        for (int k = 0; k < 32; k++) q = fmaf(sF0[nl * 32 + k], sWq[k * 32 + c], q);
        qbuf[node * 32 + c] = q * scaleN;
      }
      __syncthreads();
    } else {
      if (valid) {
        out0[node * 32 + c] = a0;
        int b = (node * 32 + c) * 3;
        out1[b] = ax; out1[b + 1] = ay; out1[b + 2] = az;
      }
      __syncthreads();
    }
  }
}

// ---------------- host launch ----------------

extern "C" void kernel_launch(void* const* d_in, const int* in_sizes, int n_in,
                              void* d_out, int out_size, void* d_ws, size_t ws_size,
                              hipStream_t stream) {
  const float* pos = (const float*)d_in[0];
  const float* f0  = (const float*)d_in[1];
  const float* f1  = (const float*)d_in[2];
  const int* src   = (const int*)d_in[3];
  const int* dst   = (const int*)d_in[4];
  const float* W1  = (const float*)d_in[5];
  const float* b1  = (const float*)d_in[6];
  const float* W2  = (const float*)d_in[7];
  const float* b2  = (const float*)d_in[8];
  const float* Wq  = (const float*)d_in[9];
  const float* Wo0 = (const float*)d_in[10];
  const float* Wo1 = (const float*)d_in[11];
  const float* Ws0 = (const float*)d_in[12];
  const float* Ws1 = (const float*)d_in[13];
  const float* bg  = (const float*)d_in[14];

  int N = in_sizes[0] / 3;
  int E = in_sizes[3];

  char* p = (char*)d_ws;
  auto alloc = [&](size_t bytes) {
    char* r = p;
    p += (bytes + 255) & ~(size_t)255;
    return r;
  };
  int* counts   = (int*)alloc((size_t)N * 4);
  int* offs     = (int*)alloc((size_t)(N + 1) * 4);
  int* cursor   = (int*)alloc((size_t)N * 4);
  int* bsums    = (int*)alloc(1024 * 4);
  int* esrcS    = (int*)alloc((size_t)E * 4);
  float4* egeoS = (float4*)alloc((size_t)E * 16);
  float2* coef  = (float2*)alloc((size_t)5 * NIV * NCH * 8);
  float* tks    = (float*)alloc((size_t)5 * HRAD * 4);
  float4* fpk   = (float4*)alloc((size_t)N * CCH * 16);
  float4* Opk   = (float4*)alloc((size_t)N * CCH * 16);
  float* qbuf   = (float*)alloc((size_t)N * CCH * 4);

  pwl_build_kernel<<<5, 256, 0, stream>>>(W1, b1, W2, b2, coef, tks);
  hipMemsetAsync(counts, 0, (size_t)N * 4, stream);
  hist_kernel<<<(E + 255) / 256, 256, 0, stream>>>(dst, counts, E);
  int nb = (N + 1023) / 1024;
  scan1_kernel<<<nb, 1024, 0, stream>>>(counts, offs, bsums, N);
  scan2_kernel<<<1, 64, 0, stream>>>(bsums, nb);
  scan3_kernel<<<(N + 1 + 255) / 256, 256, 0, stream>>>(offs, bsums, cursor, N, E);
  scatter_kernel<<<(E + 255) / 256, 256, 0, stream>>>(pos, src, dst, cursor, esrcS, egeoS, E);

  float sc8 = 1.0f / sqrtf(8.0f);
  float sc32 = 1.0f / sqrtf(32.0f);
  pack_kernel<<<512, 512, 0, stream>>>(f0, f1, Wq, sc8, fpk, qbuf, N);

  float* out0 = (float*)d_out;
  float* out1 = out0 + (size_t)N * CCH;
  for (int l = 0; l < 5; l++) {
    bool last = (l == 4);
    int ch = last ? 32 : 8;
    node_kernel<<<512, 1024, 0, stream>>>(
        fpk, qbuf, Opk, esrcS, egeoS, offs,
        coef + (size_t)l * NIV * NCH, tks + l * HRAD, ch, N);
    epi_kernel<<<512, 512, 0, stream>>>(
        Opk, fpk,
        Wo0 + l * CCH * CCH, Ws0 + l * CCH * CCH,
        Wo1 + l * CCH * CCH, Ws1 + l * CCH * CCH,
        bg + (last ? 0 : l) * CCH,
        Wq + (l + 1 <= 4 ? (l + 1) : 4) * CCH * CCH, qbuf,
        (l + 1 == 4) ? sc32 : sc8,
        out0, out1, last ? 1 : 0, N);
  }
}

// Round 6
// 961.028 us; speedup vs baseline: 4.3028x; 4.3028x over previous
//
#include <hip/hip_runtime.h>
#include <math.h>

#define CCH 32        // channels
#define NCH 224       // 7*C radial outputs
#define NIV 33        // PWL intervals
#define HRAD 32
#define ET 16         // nodes per epi block-iter

// ---------------- CSR build ----------------

__global__ void hist_kernel(const int* __restrict__ dst, int* __restrict__ counts, int E) {
  int e = blockIdx.x * 256 + threadIdx.x;
  if (e < E) atomicAdd(&counts[dst[e]], 1);
}

__global__ void scan1_kernel(const int* __restrict__ counts, int* __restrict__ offs,
                             int* __restrict__ bsums, int n) {
  __shared__ int sd[1024];
  int t = threadIdx.x;
  int i = blockIdx.x * 1024 + t;
  int v = (i < n) ? counts[i] : 0;
  sd[t] = v;
  __syncthreads();
  for (int o = 1; o < 1024; o <<= 1) {
    int add = (t >= o) ? sd[t - o] : 0;
    __syncthreads();
    sd[t] += add;
    __syncthreads();
  }
  if (i < n) offs[i] = sd[t] - v;          // block-local exclusive
  if (t == 1023) bsums[blockIdx.x] = sd[1023];
}

__global__ void scan2_kernel(int* bsums, int nb) {
  if (threadIdx.x == 0 && blockIdx.x == 0) {
    int acc = 0;
    for (int i = 0; i < nb; i++) { int v = bsums[i]; bsums[i] = acc; acc += v; }
  }
}

__global__ void scan3_kernel(int* __restrict__ offs, const int* __restrict__ bsums,
                             int* __restrict__ cursor, int n, int E) {
  int i = blockIdx.x * 256 + threadIdx.x;
  if (i < n) {
    int v = offs[i] + bsums[i >> 10];
    offs[i] = v;
    cursor[i] = v;
  } else if (i == n) {
    offs[n] = E;
  }
}

__global__ void scatter_kernel(const float* __restrict__ pos, const int* __restrict__ src,
                               const int* __restrict__ dst, int* __restrict__ cursor,
                               int* __restrict__ esrcS, float4* __restrict__ egeoS, int E) {
  int e = blockIdx.x * 256 + threadIdx.x;
  if (e >= E) return;
  int s = src[e], d = dst[e];
  float rx = pos[d * 3 + 0] - pos[s * 3 + 0];
  float ry = pos[d * 3 + 1] - pos[s * 3 + 1];
  float rz = pos[d * 3 + 2] - pos[s * 3 + 2];
  float rl = sqrtf(rx * rx + ry * ry + rz * rz);
  float inv = 1.0f / (rl + 1e-6f);
  int p = atomicAdd(&cursor[d], 1);
  esrcS[p] = s;
  egeoS[p] = make_float4(rx * inv, ry * inv, rz * inv, rl);
}

// ---------------- exact piecewise-linear collapse of the radial MLP ----------------

__global__ void pwl_build_kernel(const float* __restrict__ W1, const float* __restrict__ b1,
                                 const float* __restrict__ W2, const float* __restrict__ b2,
                                 float2* __restrict__ coef, float* __restrict__ tks) {
  int l = blockIdx.x;
  int tid = threadIdx.x;
  const float* w1 = W1 + l * HRAD;
  const float* bb1 = b1 + l * HRAD;
  const float* w2 = W2 + l * HRAD * NCH;
  const float* bb2 = b2 + l * NCH;
  __shared__ float a_s[HRAD], b_s[HRAD], t_s[HRAD], t_sorted[HRAD];
  if (tid < HRAD) {
    float a = w1[tid], b = bb1[tid];
    a_s[tid] = a; b_s[tid] = b;
    t_s[tid] = (a != 0.0f) ? (-b / a) : 1e30f;
  }
  __syncthreads();
  if (tid < HRAD) {
    float tj = t_s[tid];
    int rank = 0;
    for (int k = 0; k < HRAD; k++) {
      float tk = t_s[k];
      rank += (tk < tj) || (tk == tj && k < tid);
    }
    t_sorted[rank] = tj;
    tks[l * HRAD + tid] = tj;   // UNSORTED kinks (count-of-smaller is order-free)
  }
  __syncthreads();
  for (int idx = tid; idx < NIV * NCH; idx += blockDim.x) {
    int iv = idx / NCH;
    int k = idx - iv * NCH;
    double lo = (iv == 0) ? (double)t_sorted[0] - 1.0 : (double)t_sorted[iv - 1];
    double hi = (iv == NIV - 1) ? (double)t_sorted[HRAD - 1] + 1.0 : (double)t_sorted[iv];
    double rm = 0.5 * (lo + hi);
    if (iv == 0) rm = (double)t_sorted[0] - 1.0;
    if (iv == NIV - 1) rm = (double)t_sorted[HRAD - 1] + 1.0;
    float alpha = bb2[k];
    float beta = 0.0f;
    for (int j = 0; j < HRAD; j++) {
      if ((double)a_s[j] * rm + (double)b_s[j] > 0.0) {
        float w = w2[j * NCH + k];
        alpha = fmaf(w, b_s[j], alpha);
        beta = fmaf(w, a_s[j], beta);
      }
    }
    coef[l * (NIV * NCH) + idx] = make_float2(alpha, beta);
  }
}

// ---------------- initial pack (f0,f1 -> float4 rows) + q for layer 0 ----------------

__global__ __launch_bounds__(512) void pack_kernel(
    const float* __restrict__ f0, const float* __restrict__ f1,
    const float* __restrict__ Wq0, float scale0,
    float4* __restrict__ fpk, float* __restrict__ qbuf, int n) {
  __shared__ float sWq[1024];
  __shared__ float sF0[ET * 32];
  int tid = threadIdx.x;
  for (int i = tid; i < 1024; i += 512) sWq[i] = Wq0[i];
  __syncthreads();
  int nl = tid >> 5, c = tid & 31;
  for (int base = blockIdx.x * ET; base < n; base += gridDim.x * ET) {
    int node = base + nl;
    float v0 = 0.f, x = 0.f, y = 0.f, z = 0.f;
    if (node < n) {
      v0 = f0[node * 32 + c];
      int b = (node * 32 + c) * 3;
      x = f1[b]; y = f1[b + 1]; z = f1[b + 2];
      fpk[node * 32 + c] = make_float4(v0, x, y, z);
    }
    sF0[nl * 32 + c] = v0;
    __syncthreads();
    if (node < n) {
      float q = 0.f;
#pragma unroll
      for (int k = 0; k < 32; k++) q = fmaf(sF0[nl * 32 + k], sWq[k * 32 + c], q);
      qbuf[node * 32 + c] = q * scale0;
    }
    __syncthreads();
  }
}

// ---------------- per-node attention (softmax-weighted aggregation only) ----------------
// One wave per node. lane = c + 32*half; halves process alternating edges with
// independent online-softmax states, merged at the end via shfl_xor(32).
// Depth-2 gather pipeline via 2x unroll: two static slots (A=edges j,j+4,..;
// B=edges j+2,j+6,..), each load writes the register it is consumed from one
// full iteration later -> no register rotation, 4 gathers in flight per wave.
// Bodies share one softmax state (sequential in program order).

__global__ __launch_bounds__(1024) void node_kernel(
    const float4* __restrict__ fpk, const float* __restrict__ qbuf,
    float4* __restrict__ Opk,
    const int* __restrict__ esrcS, const float4* __restrict__ egeoS,
    const int* __restrict__ offs,
    const float2* __restrict__ coefG, const float* __restrict__ tkG,
    int ch, int n) {
  __shared__ float2 sCoef[NIV * NCH];   // 59136 B
  __shared__ float sTk[CCH];
  int tid = threadIdx.x;
  for (int i = tid; i < NIV * NCH; i += 1024) sCoef[i] = coefG[i];
  if (tid < CCH) sTk[tid] = tkG[tid];
  __syncthreads();

  int lane = tid & 63;
  int wid = tid >> 6;
  int c = lane & 31;
  int half = lane >> 5;
  float tk_c = sTk[c];

  for (int node = blockIdx.x * 16 + wid; node < n; node += gridDim.x * 16) {
    float qs = qbuf[node * 32 + c];   // pre-scaled q
    int start = offs[node], end = offs[node + 1];
    float m = -INFINITY, z = 0.0f;
    float o0 = 0.0f, o10 = 0.0f, o11 = 0.0f, o12 = 0.0f;

    int j = start + half;
    int sA = 0, sB = 0;
    float4 gA = make_float4(0, 0, 0, 0), gB = make_float4(0, 0, 0, 0);
    float4 FA = make_float4(0, 0, 0, 0), FB = make_float4(0, 0, 0, 0);
    if (j < end)     { int s = esrcS[j];     gA = egeoS[j];     FA = fpk[s * 32 + c]; }
    if (j + 2 < end) { int s = esrcS[j + 2]; gB = egeoS[j + 2]; FB = fpk[s * 32 + c]; }
    if (j + 4 < end) sA = esrcS[j + 4];
    if (j + 6 < end) sB = esrcS[j + 6];

    while (j < end) {
      // ---- body A: edge j ----
      {
        float4 g = gA;
        float4 F = FA;
        if (j + 4 < end) {          // refill slot A for edge j+4
          FA = fpk[sA * 32 + c];
          gA = egeoS[j + 4];
          if (j + 8 < end) sA = esrcS[j + 8];
        }
        unsigned long long msk = __ballot(g.w > tk_c);
        int iv = half ? (int)__popcll(msk >> 32) : (int)__popcll(msk & 0xFFFFFFFFull);
        const float2* cf = sCoef + iv * NCH + c;
        float r = g.w;
        float2 q0 = cf[0],   q1 = cf[32],  q2 = cf[64], q3 = cf[96];
        float2 q4 = cf[128], q5 = cf[160], q6 = cf[192];
        float rk00 = fmaf(q0.y, r, q0.x), rk10 = fmaf(q1.y, r, q1.x);
        float rv00 = fmaf(q2.y, r, q2.x), rv10 = fmaf(q3.y, r, q3.x);
        float rv11 = fmaf(q4.y, r, q4.x), rv01 = fmaf(q5.y, r, q5.x);
        float rv11b = fmaf(q6.y, r, q6.x);
        float dot1 = fmaf(F.y, g.x, fmaf(F.z, g.y, F.w * g.z));
        float k0 = fmaf(rk00, F.x, rk10 * dot1);
        float t = qs * k0;
        for (int o = 1; o < ch; o <<= 1) t += __shfl_xor(t, o, 64);
        float mn = fmaxf(m, t);
        float a = __expf(m - mn);
        float p = __expf(t - mn);
        m = mn;
        z = fmaf(z, a, p);
        float v0 = fmaf(rv00, F.x, rv10 * dot1);
        float sg = fmaf(rv01, F.x, rv11b * dot1);
        o0  = fmaf(o0,  a, p * v0);
        o10 = fmaf(o10, a, p * fmaf(rv11, F.y, sg * g.x));
        o11 = fmaf(o11, a, p * fmaf(rv11, F.z, sg * g.y));
        o12 = fmaf(o12, a, p * fmaf(rv11, F.w, sg * g.z));
      }
      // ---- body B: edge j+2 ----
      if (j + 2 < end) {
        float4 g = gB;
        float4 F = FB;
        if (j + 6 < end) {          // refill slot B for edge j+6
          FB = fpk[sB * 32 + c];
          gB = egeoS[j + 6];
          if (j + 10 < end) sB = esrcS[j + 10];
        }
        unsigned long long msk = __ballot(g.w > tk_c);
        int iv = half ? (int)__popcll(msk >> 32) : (int)__popcll(msk & 0xFFFFFFFFull);
        const float2* cf = sCoef + iv * NCH + c;
        float r = g.w;
        float2 q0 = cf[0],   q1 = cf[32],  q2 = cf[64], q3 = cf[96];
        float2 q4 = cf[128], q5 = cf[160], q6 = cf[192];
        float rk00 = fmaf(q0.y, r, q0.x), rk10 = fmaf(q1.y, r, q1.x);
        float rv00 = fmaf(q2.y, r, q2.x), rv10 = fmaf(q3.y, r, q3.x);
        float rv11 = fmaf(q4.y, r, q4.x), rv01 = fmaf(q5.y, r, q5.x);
        float rv11b = fmaf(q6.y, r, q6.x);
        float dot1 = fmaf(F.y, g.x, fmaf(F.z, g.y, F.w * g.z));
        float k0 = fmaf(rk00, F.x, rk10 * dot1);
        float t = qs * k0;
        for (int o = 1; o < ch; o <<= 1) t += __shfl_xor(t, o, 64);
        float mn = fmaxf(m, t);
        float a = __expf(m - mn);
        float p = __expf(t - mn);
        m = mn;
        z = fmaf(z, a, p);
        float v0 = fmaf(rv00, F.x, rv10 * dot1);
        float sg = fmaf(rv01, F.x, rv11b * dot1);
        o0  = fmaf(o0,  a, p * v0);
        o10 = fmaf(o10, a, p * fmaf(rv11, F.y, sg * g.x));
        o11 = fmaf(o11, a, p * fmaf(rv11, F.z, sg * g.y));
        o12 = fmaf(o12, a, p * fmaf(rv11, F.w, sg * g.z));
      }
      j += 4;
    }

    // ---- merge the two half-wave softmax states ----
    float mo  = __shfl_xor(m, 32, 64);
    float zo  = __shfl_xor(z, 32, 64);
    float p0  = __shfl_xor(o0, 32, 64);
    float p10 = __shfl_xor(o10, 32, 64);
    float p11 = __shfl_xor(o11, 32, 64);
    float p12 = __shfl_xor(o12, 32, 64);
    float mf = fmaxf(m, mo);
    float aA = 0.0f, aB = 0.0f;
    if (mf > -INFINITY) { aA = __expf(m - mf); aB = __expf(mo - mf); }
    float zf = z * aA + zo * aB;
    float inv = 1.0f / (zf + 1e-6f);
    if (!half) {
      Opk[node * 32 + c] = make_float4(
          (o0 * aA + p0 * aB) * inv,
          (o10 * aA + p10 * aB) * inv,
          (o11 * aA + p11 * aB) * inv,
          (o12 * aA + p12 * aB) * inv);
    }
  }
}

// ---------------- dense epilogue: out = O@Wo + f@Ws, NL, next-layer q ----------------

__global__ __launch_bounds__(512) void epi_kernel(
    const float4* __restrict__ Opk, float4* __restrict__ fpk,
    const float* __restrict__ Wo0G, const float* __restrict__ Ws0G,
    const float* __restrict__ Wo1G, const float* __restrict__ Ws1G,
    const float* __restrict__ bgG,
    const float* __restrict__ WqN, float* __restrict__ qbuf, float scaleN,
    float* __restrict__ out0, float* __restrict__ out1,
    int mode, int n) {
  __shared__ float4 sW[32 * 32];     // (wo0, ws0, wo1, ws1) 16 KB
  __shared__ float  sWq[32 * 32];    // 4 KB
  __shared__ float4 sO[ET * 32];     // 8 KB
  __shared__ float4 sF[ET * 32];     // 8 KB
  __shared__ float  sF0[ET * 32];    // 2 KB
  int tid = threadIdx.x;
  for (int i = tid; i < 1024; i += 512) {
    sW[i] = make_float4(Wo0G[i], Ws0G[i], Wo1G[i], Ws1G[i]);
    if (mode == 0) sWq[i] = WqN[i];
  }
  __syncthreads();
  int nl = tid >> 5;
  int c  = tid & 31;
  for (int base = blockIdx.x * ET; base < n; base += gridDim.x * ET) {
    int node = base + nl;
    bool valid = node < n;
    if (valid) {
      sO[tid] = Opk[node * 32 + c];
      sF[tid] = fpk[node * 32 + c];
    }
    __syncthreads();
    float a0 = 0.f, ax = 0.f, ay = 0.f, az = 0.f;
#pragma unroll
    for (int k = 0; k < 32; k++) {
      float4 O = sO[nl * 32 + k];
      float4 F = sF[nl * 32 + k];
      float4 w = sW[k * 32 + c];
      a0 = fmaf(O.x, w.x, fmaf(F.x, w.y, a0));
      ax = fmaf(O.y, w.z, fmaf(F.y, w.w, ax));
      ay = fmaf(O.z, w.z, fmaf(F.z, w.w, ay));
      az = fmaf(O.w, w.z, fmaf(F.w, w.w, az));
    }
    if (mode == 0) {
      float f0n = fmaxf(a0, 0.f);
      float n1 = sqrtf(fmaf(ax, ax, fmaf(ay, ay, az * az)));
      float gate = fmaxf(n1 + bgG[c], 0.f) / (n1 + 1e-6f);
      if (valid) fpk[node * 32 + c] = make_float4(f0n, ax * gate, ay * gate, az * gate);
      sF0[nl * 32 + c] = f0n;
      __syncthreads();
      if (valid) {
        float q = 0.f;
#pragma unroll
        for (int k = 0; k < 32; k++) q = fmaf(sF0[nl * 32 + k], sWq[k * 32 + c], q);
        qbuf[node * 32 + c] = q * scaleN;
      }
      __syncthreads();
    } else {
      if (valid) {
        out0[node * 32 + c] = a0;
        int b = (node * 32 + c) * 3;
        out1[b] = ax; out1[b + 1] = ay; out1[b + 2] = az;
      }
      __syncthreads();
    }
  }
}

// ---------------- host launch ----------------

extern "C" void kernel_launch(void* const* d_in, const int* in_sizes, int n_in,
                              void* d_out, int out_size, void* d_ws, size_t ws_size,
                              hipStream_t stream) {
  const float* pos = (const float*)d_in[0];
  const float* f0  = (const float*)d_in[1];
  const float* f1  = (const float*)d_in[2];
  const int* src   = (const int*)d_in[3];
  const int* dst   = (const int*)d_in[4];
  const float* W1  = (const float*)d_in[5];
  const float* b1  = (const float*)d_in[6];
  const float* W2  = (const float*)d_in[7];
  const float* b2  = (const float*)d_in[8];
  const float* Wq  = (const float*)d_in[9];
  const float* Wo0 = (const float*)d_in[10];
  const float* Wo1 = (const float*)d_in[11];
  const float* Ws0 = (const float*)d_in[12];
  const float* Ws1 = (const float*)d_in[13];
  const float* bg  = (const float*)d_in[14];

  int N = in_sizes[0] / 3;
  int E = in_sizes[3];

  char* p = (char*)d_ws;
  auto alloc = [&](size_t bytes) {
    char* r = p;
    p += (bytes + 255) & ~(size_t)255;
    return r;
  };
  int* counts   = (int*)alloc((size_t)N * 4);
  int* offs     = (int*)alloc((size_t)(N + 1) * 4);
  int* cursor   = (int*)alloc((size_t)N * 4);
  int* bsums    = (int*)alloc(1024 * 4);
  int* esrcS    = (int*)alloc((size_t)E * 4);
  float4* egeoS = (float4*)alloc((size_t)E * 16);
  float2* coef  = (float2*)alloc((size_t)5 * NIV * NCH * 8);
  float* tks    = (float*)alloc((size_t)5 * HRAD * 4);
  float4* fpk   = (float4*)alloc((size_t)N * CCH * 16);
  float4* Opk   = (float4*)alloc((size_t)N * CCH * 16);
  float* qbuf   = (float*)alloc((size_t)N * CCH * 4);

  pwl_build_kernel<<<5, 256, 0, stream>>>(W1, b1, W2, b2, coef, tks);
  hipMemsetAsync(counts, 0, (size_t)N * 4, stream);
  hist_kernel<<<(E + 255) / 256, 256, 0, stream>>>(dst, counts, E);
  int nb = (N + 1023) / 1024;
  scan1_kernel<<<nb, 1024, 0, stream>>>(counts, offs, bsums, N);
  scan2_kernel<<<1, 64, 0, stream>>>(bsums, nb);
  scan3_kernel<<<(N + 1 + 255) / 256, 256, 0, stream>>>(offs, bsums, cursor, N, E);
  scatter_kernel<<<(E + 255) / 256, 256, 0, stream>>>(pos, src, dst, cursor, esrcS, egeoS, E);

  float sc8 = 1.0f / sqrtf(8.0f);
  float sc32 = 1.0f / sqrtf(32.0f);
  int nblk = (N + ET - 1) / ET;
  pack_kernel<<<nblk, 512, 0, stream>>>(f0, f1, Wq, sc8, fpk, qbuf, N);

  float* out0 = (float*)d_out;
  float* out1 = out0 + (size_t)N * CCH;
  for (int l = 0; l < 5; l++) {
    bool last = (l == 4);
    int ch = last ? 32 : 8;
    node_kernel<<<512, 1024, 0, stream>>>(
        fpk, qbuf, Opk, esrcS, egeoS, offs,
        coef + (size_t)l * NIV * NCH, tks + l * HRAD, ch, N);
    epi_kernel<<<nblk, 512, 0, stream>>>(
        Opk, fpk,
        Wo0 + l * CCH * CCH, Ws0 + l * CCH * CCH,
        Wo1 + l * CCH * CCH, Ws1 + l * CCH * CCH,
        bg + (last ? 0 : l) * CCH,
        Wq + (l + 1 <= 4 ? (l + 1) : 4) * CCH * CCH, qbuf,
        (l + 1 == 4) ? sc32 : sc8,
        out0, out1, last ? 1 : 0, N);
  }
}

// Round 7
// 886.185 us; speedup vs baseline: 4.6662x; 1.0845x over previous
//
#include <hip/hip_runtime.h>
#include <math.h>

#define CCH 32        // channels
#define NCH 224       // 7*C radial outputs
#define NIV 33        // PWL intervals
#define HRAD 32
#define ET 16         // nodes per epi block-iter

// ---------------- CSR build ----------------

__global__ void hist_kernel(const int* __restrict__ dst, int* __restrict__ counts, int E) {
  int e = blockIdx.x * 256 + threadIdx.x;
  if (e < E) atomicAdd(&counts[dst[e]], 1);
}

__global__ void scan1_kernel(const int* __restrict__ counts, int* __restrict__ offs,
                             int* __restrict__ bsums, int n) {
  __shared__ int sd[1024];
  int t = threadIdx.x;
  int i = blockIdx.x * 1024 + t;
  int v = (i < n) ? counts[i] : 0;
  sd[t] = v;
  __syncthreads();
  for (int o = 1; o < 1024; o <<= 1) {
    int add = (t >= o) ? sd[t - o] : 0;
    __syncthreads();
    sd[t] += add;
    __syncthreads();
  }
  if (i < n) offs[i] = sd[t] - v;          // block-local exclusive
  if (t == 1023) bsums[blockIdx.x] = sd[1023];
}

__global__ void scan2_kernel(int* bsums, int nb) {
  if (threadIdx.x == 0 && blockIdx.x == 0) {
    int acc = 0;
    for (int i = 0; i < nb; i++) { int v = bsums[i]; bsums[i] = acc; acc += v; }
  }
}

__global__ void scan3_kernel(int* __restrict__ offs, const int* __restrict__ bsums,
                             int* __restrict__ cursor, int n, int E) {
  int i = blockIdx.x * 256 + threadIdx.x;
  if (i < n) {
    int v = offs[i] + bsums[i >> 10];
    offs[i] = v;
    cursor[i] = v;
  } else if (i == n) {
    offs[n] = E;
  }
}

__global__ void scatter_kernel(const float* __restrict__ pos, const int* __restrict__ src,
                               const int* __restrict__ dst, int* __restrict__ cursor,
                               int* __restrict__ esrcS, float4* __restrict__ egeoS, int E) {
  int e = blockIdx.x * 256 + threadIdx.x;
  if (e >= E) return;
  int s = src[e], d = dst[e];
  float rx = pos[d * 3 + 0] - pos[s * 3 + 0];
  float ry = pos[d * 3 + 1] - pos[s * 3 + 1];
  float rz = pos[d * 3 + 2] - pos[s * 3 + 2];
  float rl = sqrtf(rx * rx + ry * ry + rz * rz);
  float inv = 1.0f / (rl + 1e-6f);
  int p = atomicAdd(&cursor[d], 1);
  esrcS[p] = s;
  egeoS[p] = make_float4(rx * inv, ry * inv, rz * inv, rl);
}

// ---------------- exact piecewise-linear collapse of the radial MLP ----------------
// Parallelized: one block per (layer, interval) pair -> 165 blocks.

__global__ void pwl_build_kernel(const float* __restrict__ W1, const float* __restrict__ b1,
                                 const float* __restrict__ W2, const float* __restrict__ b2,
                                 float2* __restrict__ coef, float* __restrict__ tks) {
  int l = blockIdx.x / NIV;
  int iv = blockIdx.x - l * NIV;
  int tid = threadIdx.x;
  const float* w1 = W1 + l * HRAD;
  const float* bb1 = b1 + l * HRAD;
  const float* w2 = W2 + l * HRAD * NCH;
  const float* bb2 = b2 + l * NCH;
  __shared__ float a_s[HRAD], b_s[HRAD], t_s[HRAD], t_sorted[HRAD];
  if (tid < HRAD) {
    float a = w1[tid], b = bb1[tid];
    a_s[tid] = a; b_s[tid] = b;
    t_s[tid] = (a != 0.0f) ? (-b / a) : 1e30f;
  }
  __syncthreads();
  if (tid < HRAD) {
    float tj = t_s[tid];
    int rank = 0;
    for (int k = 0; k < HRAD; k++) {
      float tk = t_s[k];
      rank += (tk < tj) || (tk == tj && k < tid);
    }
    t_sorted[rank] = tj;
    if (iv == 0) tks[l * HRAD + tid] = tj;   // UNSORTED kinks (count-of-smaller is order-free)
  }
  __syncthreads();
  if (tid < NCH) {
    int k = tid;
    double lo = (iv == 0) ? (double)t_sorted[0] - 1.0 : (double)t_sorted[iv - 1];
    double hi = (iv == NIV - 1) ? (double)t_sorted[HRAD - 1] + 1.0 : (double)t_sorted[iv];
    double rm = 0.5 * (lo + hi);
    if (iv == 0) rm = (double)t_sorted[0] - 1.0;
    if (iv == NIV - 1) rm = (double)t_sorted[HRAD - 1] + 1.0;
    float alpha = bb2[k];
    float beta = 0.0f;
    for (int j = 0; j < HRAD; j++) {
      if ((double)a_s[j] * rm + (double)b_s[j] > 0.0) {
        float w = w2[j * NCH + k];
        alpha = fmaf(w, b_s[j], alpha);
        beta = fmaf(w, a_s[j], beta);
      }
    }
    coef[l * (NIV * NCH) + iv * NCH + k] = make_float2(alpha, beta);
  }
}

// ---------------- initial pack (f0,f1 -> float4 rows) + q for layer 0 ----------------

__global__ __launch_bounds__(512) void pack_kernel(
    const float* __restrict__ f0, const float* __restrict__ f1,
    const float* __restrict__ Wq0, float scale0,
    float4* __restrict__ fpk, float* __restrict__ qbuf, int n) {
  __shared__ float sWq[1024];
  __shared__ float sF0[ET * 32];
  int tid = threadIdx.x;
  for (int i = tid; i < 1024; i += 512) sWq[i] = Wq0[i];
  __syncthreads();
  int nl = tid >> 5, c = tid & 31;
  for (int base = blockIdx.x * ET; base < n; base += gridDim.x * ET) {
    int node = base + nl;
    float v0 = 0.f, x = 0.f, y = 0.f, z = 0.f;
    if (node < n) {
      v0 = f0[node * 32 + c];
      int b = (node * 32 + c) * 3;
      x = f1[b]; y = f1[b + 1]; z = f1[b + 2];
      fpk[node * 32 + c] = make_float4(v0, x, y, z);
    }
    sF0[nl * 32 + c] = v0;
    __syncthreads();
    if (node < n) {
      float q = 0.f;
#pragma unroll
      for (int k = 0; k < 32; k++) q = fmaf(sF0[nl * 32 + k], sWq[k * 32 + c], q);
      qbuf[node * 32 + c] = q * scale0;
    }
    __syncthreads();
  }
}

// ---------------- per-node attention (softmax-weighted aggregation only) ----------------
// EXACT R2 structure (known-good 105 us): one wave per node, lane = c + 32*half,
// halves process alternating edges with depth-1 prefetch (load writes the register
// consumed next iteration; no rotation). Only delta vs R2: CH is a template param
// so the logit shfl reduction fully unrolls (removes loop control only).

template <int CH>
__global__ __launch_bounds__(1024) void node_kernel(
    const float4* __restrict__ fpk, const float* __restrict__ qbuf,
    float4* __restrict__ Opk,
    const int* __restrict__ esrcS, const float4* __restrict__ egeoS,
    const int* __restrict__ offs,
    const float2* __restrict__ coefG, const float* __restrict__ tkG,
    int n) {
  __shared__ float2 sCoef[NIV * NCH];   // 59136 B
  __shared__ float sTk[CCH];
  int tid = threadIdx.x;
  for (int i = tid; i < NIV * NCH; i += 1024) sCoef[i] = coefG[i];
  if (tid < CCH) sTk[tid] = tkG[tid];
  __syncthreads();

  int lane = tid & 63;
  int wid = tid >> 6;
  int c = lane & 31;
  int half = lane >> 5;
  float tk_c = sTk[c];

  for (int node = blockIdx.x * 16 + wid; node < n; node += gridDim.x * 16) {
    float qs = qbuf[node * 32 + c];   // pre-scaled q
    int start = offs[node], end = offs[node + 1];
    float m = -INFINITY, z = 0.0f;
    float o0 = 0.0f, o10 = 0.0f, o11 = 0.0f, o12 = 0.0f;

    int j = start + half;
    int sB = 0;
    float4 gA = make_float4(0, 0, 0, 0), gB = make_float4(0, 0, 0, 0);
    float4 FA = make_float4(0, 0, 0, 0);
    if (j < end) {
      int sA = esrcS[j];
      gA = egeoS[j];
      FA = fpk[sA * 32 + c];
    }
    if (j + 2 < end) { sB = esrcS[j + 2]; gB = egeoS[j + 2]; }

    while (j < end) {
      float4 g = gA;
      float4 F = FA;
      int j2 = j + 2;
      if (j2 < end) {   // prefetch next edge's packed features, next-next record
        FA = fpk[sB * 32 + c];
        gA = gB;
        if (j2 + 2 < end) { sB = esrcS[j2 + 2]; gB = egeoS[j2 + 2]; }
      }
      unsigned long long msk = __ballot(g.w > tk_c);
      int iv = half ? (int)__popcll(msk >> 32) : (int)__popcll(msk & 0xFFFFFFFFull);
      const float2* cf = sCoef + iv * NCH + c;
      float r = g.w;
      float2 q0 = cf[0],   q1 = cf[32],  q2 = cf[64], q3 = cf[96];
      float2 q4 = cf[128], q5 = cf[160], q6 = cf[192];
      float rk00 = fmaf(q0.y, r, q0.x), rk10 = fmaf(q1.y, r, q1.x);
      float rv00 = fmaf(q2.y, r, q2.x), rv10 = fmaf(q3.y, r, q3.x);
      float rv11 = fmaf(q4.y, r, q4.x), rv01 = fmaf(q5.y, r, q5.x);
      float rv11b = fmaf(q6.y, r, q6.x);
      float dot1 = fmaf(F.y, g.x, fmaf(F.z, g.y, F.w * g.z));
      float k0 = fmaf(rk00, F.x, rk10 * dot1);
      float t = qs * k0;
#pragma unroll
      for (int o = 1; o < CH; o <<= 1) t += __shfl_xor(t, o, 64);
      float mn = fmaxf(m, t);
      float a = __expf(m - mn);
      float p = __expf(t - mn);
      m = mn;
      z = fmaf(z, a, p);
      float v0 = fmaf(rv00, F.x, rv10 * dot1);
      float sg = fmaf(rv01, F.x, rv11b * dot1);
      o0  = fmaf(o0,  a, p * v0);
      o10 = fmaf(o10, a, p * fmaf(rv11, F.y, sg * g.x));
      o11 = fmaf(o11, a, p * fmaf(rv11, F.z, sg * g.y));
      o12 = fmaf(o12, a, p * fmaf(rv11, F.w, sg * g.z));
      j = j2;
    }

    // ---- merge the two half-wave softmax states ----
    float mo  = __shfl_xor(m, 32, 64);
    float zo  = __shfl_xor(z, 32, 64);
    float p0  = __shfl_xor(o0, 32, 64);
    float p10 = __shfl_xor(o10, 32, 64);
    float p11 = __shfl_xor(o11, 32, 64);
    float p12 = __shfl_xor(o12, 32, 64);
    float mf = fmaxf(m, mo);
    float aA = 0.0f, aB = 0.0f;
    if (mf > -INFINITY) { aA = __expf(m - mf); aB = __expf(mo - mf); }
    float zf = z * aA + zo * aB;
    float inv = 1.0f / (zf + 1e-6f);
    if (!half) {
      Opk[node * 32 + c] = make_float4(
          (o0 * aA + p0 * aB) * inv,
          (o10 * aA + p10 * aB) * inv,
          (o11 * aA + p11 * aB) * inv,
          (o12 * aA + p12 * aB) * inv);
    }
  }
}

// ---------------- dense epilogue: out = O@Wo + f@Ws, NL, next-layer q ----------------

__global__ __launch_bounds__(512) void epi_kernel(
    const float4* __restrict__ Opk, float4* __restrict__ fpk,
    const float* __restrict__ Wo0G, const float* __restrict__ Ws0G,
    const float* __restrict__ Wo1G, const float* __restrict__ Ws1G,
    const float* __restrict__ bgG,
    const float* __restrict__ WqN, float* __restrict__ qbuf, float scaleN,
    float* __restrict__ out0, float* __restrict__ out1,
    int mode, int n) {
  __shared__ float4 sW[32 * 32];     // (wo0, ws0, wo1, ws1) 16 KB
  __shared__ float  sWq[32 * 32];    // 4 KB
  __shared__ float4 sO[ET * 32];     // 8 KB
  __shared__ float4 sF[ET * 32];     // 8 KB
  __shared__ float  sF0[ET * 32];    // 2 KB
  int tid = threadIdx.x;
  for (int i = tid; i < 1024; i += 512) {
    sW[i] = make_float4(Wo0G[i], Ws0G[i], Wo1G[i], Ws1G[i]);
    if (mode == 0) sWq[i] = WqN[i];
  }
  __syncthreads();
  int nl = tid >> 5;
  int c  = tid & 31;
  for (int base = blockIdx.x * ET; base < n; base += gridDim.x * ET) {
    int node = base + nl;
    bool valid = node < n;
    if (valid) {
      sO[tid] = Opk[node * 32 + c];
      sF[tid] = fpk[node * 32 + c];
    }
    __syncthreads();
    float a0 = 0.f, ax = 0.f, ay = 0.f, az = 0.f;
#pragma unroll
    for (int k = 0; k < 32; k++) {
      float4 O = sO[nl * 32 + k];
      float4 F = sF[nl * 32 + k];
      float4 w = sW[k * 32 + c];
      a0 = fmaf(O.x, w.x, fmaf(F.x, w.y, a0));
      ax = fmaf(O.y, w.z, fmaf(F.y, w.w, ax));
      ay = fmaf(O.z, w.z, fmaf(F.z, w.w, ay));
      az = fmaf(O.w, w.z, fmaf(F.w, w.w, az));
    }
    if (mode == 0) {
      float f0n = fmaxf(a0, 0.f);
      float n1 = sqrtf(fmaf(ax, ax, fmaf(ay, ay, az * az)));
      float gate = fmaxf(n1 + bgG[c], 0.f) / (n1 + 1e-6f);
      if (valid) fpk[node * 32 + c] = make_float4(f0n, ax * gate, ay * gate, az * gate);
      sF0[nl * 32 + c] = f0n;
      __syncthreads();
      if (valid) {
        float q = 0.f;
#pragma unroll
        for (int k = 0; k < 32; k++) q = fmaf(sF0[nl * 32 + k], sWq[k * 32 + c], q);
        qbuf[node * 32 + c] = q * scaleN;
      }
      __syncthreads();
    } else {
      if (valid) {
        out0[node * 32 + c] = a0;
        int b = (node * 32 + c) * 3;
        out1[b] = ax; out1[b + 1] = ay; out1[b + 2] = az;
      }
      __syncthreads();
    }
  }
}

// ---------------- host launch ----------------

extern "C" void kernel_launch(void* const* d_in, const int* in_sizes, int n_in,
                              void* d_out, int out_size, void* d_ws, size_t ws_size,
                              hipStream_t stream) {
  const float* pos = (const float*)d_in[0];
  const float* f0  = (const float*)d_in[1];
  const float* f1  = (const float*)d_in[2];
  const int* src   = (const int*)d_in[3];
  const int* dst   = (const int*)d_in[4];
  const float* W1  = (const float*)d_in[5];
  const float* b1  = (const float*)d_in[6];
  const float* W2  = (const float*)d_in[7];
  const float* b2  = (const float*)d_in[8];
  const float* Wq  = (const float*)d_in[9];
  const float* Wo0 = (const float*)d_in[10];
  const float* Wo1 = (const float*)d_in[11];
  const float* Ws0 = (const float*)d_in[12];
  const float* Ws1 = (const float*)d_in[13];
  const float* bg  = (const float*)d_in[14];

  int N = in_sizes[0] / 3;
  int E = in_sizes[3];

  char* p = (char*)d_ws;
  auto alloc = [&](size_t bytes) {
    char* r = p;
    p += (bytes + 255) & ~(size_t)255;
    return r;
  };
  int* counts   = (int*)alloc((size_t)N * 4);
  int* offs     = (int*)alloc((size_t)(N + 1) * 4);
  int* cursor   = (int*)alloc((size_t)N * 4);
  int* bsums    = (int*)alloc(1024 * 4);
  int* esrcS    = (int*)alloc((size_t)E * 4);
  float4* egeoS = (float4*)alloc((size_t)E * 16);
  float2* coef  = (float2*)alloc((size_t)5 * NIV * NCH * 8);
  float* tks    = (float*)alloc((size_t)5 * HRAD * 4);
  float4* fpk   = (float4*)alloc((size_t)N * CCH * 16);
  float4* Opk   = (float4*)alloc((size_t)N * CCH * 16);
  float* qbuf   = (float*)alloc((size_t)N * CCH * 4);

  pwl_build_kernel<<<5 * NIV, 256, 0, stream>>>(W1, b1, W2, b2, coef, tks);
  hipMemsetAsync(counts, 0, (size_t)N * 4, stream);
  hist_kernel<<<(E + 255) / 256, 256, 0, stream>>>(dst, counts, E);
  int nb = (N + 1023) / 1024;
  scan1_kernel<<<nb, 1024, 0, stream>>>(counts, offs, bsums, N);
  scan2_kernel<<<1, 64, 0, stream>>>(bsums, nb);
  scan3_kernel<<<(N + 1 + 255) / 256, 256, 0, stream>>>(offs, bsums, cursor, N, E);
  scatter_kernel<<<(E + 255) / 256, 256, 0, stream>>>(pos, src, dst, cursor, esrcS, egeoS, E);

  float sc8 = 1.0f / sqrtf(8.0f);
  float sc32 = 1.0f / sqrtf(32.0f);
  int nblk = (N + ET - 1) / ET;
  pack_kernel<<<nblk, 512, 0, stream>>>(f0, f1, Wq, sc8, fpk, qbuf, N);

  float* out0 = (float*)d_out;
  float* out1 = out0 + (size_t)N * CCH;
  for (int l = 0; l < 5; l++) {
    bool last = (l == 4);
    if (last) {
      node_kernel<32><<<512, 1024, 0, stream>>>(
          fpk, qbuf, Opk, esrcS, egeoS, offs,
          coef + (size_t)l * NIV * NCH, tks + l * HRAD, N);
    } else {
      node_kernel<8><<<512, 1024, 0, stream>>>(
          fpk, qbuf, Opk, esrcS, egeoS, offs,
          coef + (size_t)l * NIV * NCH, tks + l * HRAD, N);
    }
    epi_kernel<<<nblk, 512, 0, stream>>>(
        Opk, fpk,
        Wo0 + l * CCH * CCH, Ws0 + l * CCH * CCH,
        Wo1 + l * CCH * CCH, Ws1 + l * CCH * CCH,
        bg + (last ? 0 : l) * CCH,
        Wq + (l + 1 <= 4 ? (l + 1) : 4) * CCH * CCH, qbuf,
        (l + 1 == 4) ? sc32 : sc8,
        out0, out1, last ? 1 : 0, N);
  }
}

// Round 8
// 793.527 us; speedup vs baseline: 5.2110x; 1.1168x over previous
//
#include <hip/hip_runtime.h>
#include <math.h>

#define CCH 32        // channels
#define NCH 224       // 7*C radial outputs
#define NIV 33        // PWL intervals
#define HRAD 32
#define ET 16         // nodes per epi block-iter

// ---------------- CSR build ----------------

__global__ void hist_kernel(const int* __restrict__ dst, int* __restrict__ counts, int E) {
  int e = blockIdx.x * 256 + threadIdx.x;
  if (e < E) atomicAdd(&counts[dst[e]], 1);
}

__global__ void scan1_kernel(const int* __restrict__ counts, int* __restrict__ offs,
                             int* __restrict__ bsums, int n) {
  __shared__ int sd[1024];
  int t = threadIdx.x;
  int i = blockIdx.x * 1024 + t;
  int v = (i < n) ? counts[i] : 0;
  sd[t] = v;
  __syncthreads();
  for (int o = 1; o < 1024; o <<= 1) {
    int add = (t >= o) ? sd[t - o] : 0;
    __syncthreads();
    sd[t] += add;
    __syncthreads();
  }
  if (i < n) offs[i] = sd[t] - v;          // block-local exclusive
  if (t == 1023) bsums[blockIdx.x] = sd[1023];
}

__global__ void scan2_kernel(int* bsums, int nb) {
  if (threadIdx.x == 0 && blockIdx.x == 0) {
    int acc = 0;
    for (int i = 0; i < nb; i++) { int v = bsums[i]; bsums[i] = acc; acc += v; }
  }
}

__global__ void scan3_kernel(int* __restrict__ offs, const int* __restrict__ bsums,
                             int* __restrict__ cursor, int n, int E) {
  int i = blockIdx.x * 256 + threadIdx.x;
  if (i < n) {
    int v = offs[i] + bsums[i >> 10];
    offs[i] = v;
    cursor[i] = v;
  } else if (i == n) {
    offs[n] = E;
  }
}

__global__ void scatter_kernel(const float* __restrict__ pos, const int* __restrict__ src,
                               const int* __restrict__ dst, int* __restrict__ cursor,
                               int* __restrict__ esrcS, float4* __restrict__ egeoS, int E) {
  int e = blockIdx.x * 256 + threadIdx.x;
  if (e >= E) return;
  int s = src[e], d = dst[e];
  float rx = pos[d * 3 + 0] - pos[s * 3 + 0];
  float ry = pos[d * 3 + 1] - pos[s * 3 + 1];
  float rz = pos[d * 3 + 2] - pos[s * 3 + 2];
  float rl = sqrtf(rx * rx + ry * ry + rz * rz);
  float inv = 1.0f / (rl + 1e-6f);
  int p = atomicAdd(&cursor[d], 1);
  esrcS[p] = s;
  egeoS[p] = make_float4(rx * inv, ry * inv, rz * inv, rl);
}

// ---------------- exact piecewise-linear collapse of the radial MLP ----------------
// Parallelized: one block per (layer, interval) pair -> 165 blocks.

__global__ void pwl_build_kernel(const float* __restrict__ W1, const float* __restrict__ b1,
                                 const float* __restrict__ W2, const float* __restrict__ b2,
                                 float2* __restrict__ coef, float* __restrict__ tks) {
  int l = blockIdx.x / NIV;
  int iv = blockIdx.x - l * NIV;
  int tid = threadIdx.x;
  const float* w1 = W1 + l * HRAD;
  const float* bb1 = b1 + l * HRAD;
  const float* w2 = W2 + l * HRAD * NCH;
  const float* bb2 = b2 + l * NCH;
  __shared__ float a_s[HRAD], b_s[HRAD], t_s[HRAD], t_sorted[HRAD];
  if (tid < HRAD) {
    float a = w1[tid], b = bb1[tid];
    a_s[tid] = a; b_s[tid] = b;
    t_s[tid] = (a != 0.0f) ? (-b / a) : 1e30f;
  }
  __syncthreads();
  if (tid < HRAD) {
    float tj = t_s[tid];
    int rank = 0;
    for (int k = 0; k < HRAD; k++) {
      float tk = t_s[k];
      rank += (tk < tj) || (tk == tj && k < tid);
    }
    t_sorted[rank] = tj;
    if (iv == 0) tks[l * HRAD + tid] = tj;   // UNSORTED kinks (count-of-smaller is order-free)
  }
  __syncthreads();
  if (tid < NCH) {
    int k = tid;
    double lo = (iv == 0) ? (double)t_sorted[0] - 1.0 : (double)t_sorted[iv - 1];
    double hi = (iv == NIV - 1) ? (double)t_sorted[HRAD - 1] + 1.0 : (double)t_sorted[iv];
    double rm = 0.5 * (lo + hi);
    if (iv == 0) rm = (double)t_sorted[0] - 1.0;
    if (iv == NIV - 1) rm = (double)t_sorted[HRAD - 1] + 1.0;
    float alpha = bb2[k];
    float beta = 0.0f;
    for (int j = 0; j < HRAD; j++) {
      if ((double)a_s[j] * rm + (double)b_s[j] > 0.0) {
        float w = w2[j * NCH + k];
        alpha = fmaf(w, b_s[j], alpha);
        beta = fmaf(w, a_s[j], beta);
      }
    }
    coef[l * (NIV * NCH) + iv * NCH + k] = make_float2(alpha, beta);
  }
}

// ---------------- initial pack (f0,f1 -> float4 rows) + q for layer 0 ----------------

__global__ __launch_bounds__(512) void pack_kernel(
    const float* __restrict__ f0, const float* __restrict__ f1,
    const float* __restrict__ Wq0, float scale0,
    float4* __restrict__ fpk, float* __restrict__ qbuf, int n) {
  __shared__ float sWq[1024];
  __shared__ float sF0[ET * 32];
  int tid = threadIdx.x;
  for (int i = tid; i < 1024; i += 512) sWq[i] = Wq0[i];
  __syncthreads();
  int nl = tid >> 5, c = tid & 31;
  for (int base = blockIdx.x * ET; base < n; base += gridDim.x * ET) {
    int node = base + nl;
    float v0 = 0.f, x = 0.f, y = 0.f, z = 0.f;
    if (node < n) {
      v0 = f0[(size_t)node * 32 + c];
      size_t b = ((size_t)node * 32 + c) * 3;
      x = f1[b]; y = f1[b + 1]; z = f1[b + 2];
      fpk[(size_t)node * 32 + c] = make_float4(v0, x, y, z);
    }
    sF0[nl * 32 + c] = v0;
    __syncthreads();
    if (node < n) {
      float q = 0.f;
#pragma unroll
      for (int k = 0; k < 32; k++) q = fmaf(sF0[nl * 32 + k], sWq[k * 32 + c], q);
      qbuf[(size_t)node * 32 + c] = q * scale0;
    }
    __syncthreads();
  }
}

// ---------------- per-node attention (softmax-weighted aggregation only) ----------------
// EXACT R2 structure (empirical optimum: 105 us, VALU 75%). One wave per node.
// lane = c + 32*half; halves process alternating edges with independent
// online-softmax states, merged at the end via shfl_xor(32). Depth-1 prefetch,
// runtime `ch` shfl loop, size_t indexing — DO NOT perturb (R3/R4/R6/R7 all
// regressed this loop: unrolled shfl, precomputed intervals, deeper pipelines
// each traded VALU-busy for more stall).

__global__ __launch_bounds__(1024) void node_kernel(
    const float4* __restrict__ fpk, const float* __restrict__ qbuf,
    float4* __restrict__ Opk,
    const int* __restrict__ esrcS, const float4* __restrict__ egeoS,
    const int* __restrict__ offs,
    const float2* __restrict__ coefG, const float* __restrict__ tkG,
    int ch, int n) {
  __shared__ float2 sCoef[NIV * NCH];   // 59136 B
  __shared__ float sTk[CCH];
  int tid = threadIdx.x;
  for (int i = tid; i < NIV * NCH; i += 1024) sCoef[i] = coefG[i];
  if (tid < CCH) sTk[tid] = tkG[tid];
  __syncthreads();

  int lane = tid & 63;
  int wid = tid >> 6;
  int c = lane & 31;
  int half = lane >> 5;
  float tk_c = sTk[c];

  for (int node = blockIdx.x * 16 + wid; node < n; node += gridDim.x * 16) {
    float qs = qbuf[(size_t)node * 32 + c];   // pre-scaled q
    int start = offs[node], end = offs[node + 1];
    float m = -INFINITY, z = 0.0f;
    float o0 = 0.0f, o10 = 0.0f, o11 = 0.0f, o12 = 0.0f;

    int j = start + half;
    int sB = 0;
    float4 gA = make_float4(0, 0, 0, 0), gB = make_float4(0, 0, 0, 0);
    float4 FA = make_float4(0, 0, 0, 0);
    if (j < end) {
      int sA = esrcS[j];
      gA = egeoS[j];
      FA = fpk[(size_t)sA * 32 + c];
    }
    if (j + 2 < end) { sB = esrcS[j + 2]; gB = egeoS[j + 2]; }

    while (j < end) {
      float4 g = gA;
      float4 F = FA;
      int j2 = j + 2;
      if (j2 < end) {   // prefetch next edge's packed features, next-next record
        FA = fpk[(size_t)sB * 32 + c];
        gA = gB;
        if (j2 + 2 < end) { sB = esrcS[j2 + 2]; gB = egeoS[j2 + 2]; }
      }
      unsigned long long msk = __ballot(g.w > tk_c);
      int iv = half ? (int)__popcll(msk >> 32) : (int)__popcll(msk & 0xFFFFFFFFull);
      const float2* cf = sCoef + iv * NCH + c;
      float r = g.w;
      float2 q0 = cf[0],   q1 = cf[32],  q2 = cf[64], q3 = cf[96];
      float2 q4 = cf[128], q5 = cf[160], q6 = cf[192];
      float rk00 = fmaf(q0.y, r, q0.x), rk10 = fmaf(q1.y, r, q1.x);
      float rv00 = fmaf(q2.y, r, q2.x), rv10 = fmaf(q3.y, r, q3.x);
      float rv11 = fmaf(q4.y, r, q4.x), rv01 = fmaf(q5.y, r, q5.x);
      float rv11b = fmaf(q6.y, r, q6.x);
      float dot1 = fmaf(F.y, g.x, fmaf(F.z, g.y, F.w * g.z));
      float k0 = fmaf(rk00, F.x, rk10 * dot1);
      float t = qs * k0;
      for (int o = 1; o < ch; o <<= 1) t += __shfl_xor(t, o, 64);
      float mn = fmaxf(m, t);
      float a = __expf(m - mn);
      float p = __expf(t - mn);
      m = mn;
      z = fmaf(z, a, p);
      float v0 = fmaf(rv00, F.x, rv10 * dot1);
      float sg = fmaf(rv01, F.x, rv11b * dot1);
      o0  = fmaf(o0,  a, p * v0);
      o10 = fmaf(o10, a, p * fmaf(rv11, F.y, sg * g.x));
      o11 = fmaf(o11, a, p * fmaf(rv11, F.z, sg * g.y));
      o12 = fmaf(o12, a, p * fmaf(rv11, F.w, sg * g.z));
      j = j2;
    }

    // ---- merge the two half-wave softmax states ----
    float mo  = __shfl_xor(m, 32, 64);
    float zo  = __shfl_xor(z, 32, 64);
    float p0  = __shfl_xor(o0, 32, 64);
    float p10 = __shfl_xor(o10, 32, 64);
    float p11 = __shfl_xor(o11, 32, 64);
    float p12 = __shfl_xor(o12, 32, 64);
    float mf = fmaxf(m, mo);
    float aA = 0.0f, aB = 0.0f;
    if (mf > -INFINITY) { aA = __expf(m - mf); aB = __expf(mo - mf); }
    float zf = z * aA + zo * aB;
    float inv = 1.0f / (zf + 1e-6f);
    if (!half) {
      Opk[(size_t)node * 32 + c] = make_float4(
          (o0 * aA + p0 * aB) * inv,
          (o10 * aA + p10 * aB) * inv,
          (o11 * aA + p11 * aB) * inv,
          (o12 * aA + p12 * aB) * inv);
    }
  }
}

// ---------------- dense epilogue: out = O@Wo + f@Ws, NL, next-layer q ----------------

__global__ __launch_bounds__(512) void epi_kernel(
    const float4* __restrict__ Opk, float4* __restrict__ fpk,
    const float* __restrict__ Wo0G, const float* __restrict__ Ws0G,
    const float* __restrict__ Wo1G, const float* __restrict__ Ws1G,
    const float* __restrict__ bgG,
    const float* __restrict__ WqN, float* __restrict__ qbuf, float scaleN,
    float* __restrict__ out0, float* __restrict__ out1,
    int mode, int n) {
  __shared__ float4 sW[32 * 32];     // (wo0, ws0, wo1, ws1) 16 KB
  __shared__ float  sWq[32 * 32];    // 4 KB
  __shared__ float4 sO[ET * 32];     // 8 KB
  __shared__ float4 sF[ET * 32];     // 8 KB
  __shared__ float  sF0[ET * 32];    // 2 KB
  int tid = threadIdx.x;
  for (int i = tid; i < 1024; i += 512) {
    sW[i] = make_float4(Wo0G[i], Ws0G[i], Wo1G[i], Ws1G[i]);
    if (mode == 0) sWq[i] = WqN[i];
  }
  __syncthreads();
  int nl = tid >> 5;
  int c  = tid & 31;
  for (int base = blockIdx.x * ET; base < n; base += gridDim.x * ET) {
    int node = base + nl;
    bool valid = node < n;
    if (valid) {
      sO[tid] = Opk[(size_t)node * 32 + c];
      sF[tid] = fpk[(size_t)node * 32 + c];
    }
    __syncthreads();
    float a0 = 0.f, ax = 0.f, ay = 0.f, az = 0.f;
#pragma unroll
    for (int k = 0; k < 32; k++) {
      float4 O = sO[nl * 32 + k];
      float4 F = sF[nl * 32 + k];
      float4 w = sW[k * 32 + c];
      a0 = fmaf(O.x, w.x, fmaf(F.x, w.y, a0));
      ax = fmaf(O.y, w.z, fmaf(F.y, w.w, ax));
      ay = fmaf(O.z, w.z, fmaf(F.z, w.w, ay));
      az = fmaf(O.w, w.z, fmaf(F.w, w.w, az));
    }
    if (mode == 0) {
      float f0n = fmaxf(a0, 0.f);
      float n1 = sqrtf(fmaf(ax, ax, fmaf(ay, ay, az * az)));
      float gate = fmaxf(n1 + bgG[c], 0.f) / (n1 + 1e-6f);
      if (valid) fpk[(size_t)node * 32 + c] = make_float4(f0n, ax * gate, ay * gate, az * gate);
      sF0[nl * 32 + c] = f0n;
      __syncthreads();
      if (valid) {
        float q = 0.f;
#pragma unroll
        for (int k = 0; k < 32; k++) q = fmaf(sF0[nl * 32 + k], sWq[k * 32 + c], q);
        qbuf[(size_t)node * 32 + c] = q * scaleN;
      }
      __syncthreads();
    } else {
      if (valid) {
        out0[(size_t)node * 32 + c] = a0;
        size_t b = ((size_t)node * 32 + c) * 3;
        out1[b] = ax; out1[b + 1] = ay; out1[b + 2] = az;
      }
      __syncthreads();
    }
  }
}

// ---------------- host launch ----------------

extern "C" void kernel_launch(void* const* d_in, const int* in_sizes, int n_in,
                              void* d_out, int out_size, void* d_ws, size_t ws_size,
                              hipStream_t stream) {
  const float* pos = (const float*)d_in[0];
  const float* f0  = (const float*)d_in[1];
  const float* f1  = (const float*)d_in[2];
  const int* src   = (const int*)d_in[3];
  const int* dst   = (const int*)d_in[4];
  const float* W1  = (const float*)d_in[5];
  const float* b1  = (const float*)d_in[6];
  const float* W2  = (const float*)d_in[7];
  const float* b2  = (const float*)d_in[8];
  const float* Wq  = (const float*)d_in[9];
  const float* Wo0 = (const float*)d_in[10];
  const float* Wo1 = (const float*)d_in[11];
  const float* Ws0 = (const float*)d_in[12];
  const float* Ws1 = (const float*)d_in[13];
  const float* bg  = (const float*)d_in[14];

  int N = in_sizes[0] / 3;
  int E = in_sizes[3];

  char* p = (char*)d_ws;
  auto alloc = [&](size_t bytes) {
    char* r = p;
    p += (bytes + 255) & ~(size_t)255;
    return r;
  };
  int* counts   = (int*)alloc((size_t)N * 4);
  int* offs     = (int*)alloc((size_t)(N + 1) * 4);
  int* cursor   = (int*)alloc((size_t)N * 4);
  int* bsums    = (int*)alloc(1024 * 4);
  int* esrcS    = (int*)alloc((size_t)E * 4);
  float4* egeoS = (float4*)alloc((size_t)E * 16);
  float2* coef  = (float2*)alloc((size_t)5 * NIV * NCH * 8);
  float* tks    = (float*)alloc((size_t)5 * HRAD * 4);
  float4* fpk   = (float4*)alloc((size_t)N * CCH * 16);
  float4* Opk   = (float4*)alloc((size_t)N * CCH * 16);
  float* qbuf   = (float*)alloc((size_t)N * CCH * 4);

  pwl_build_kernel<<<5 * NIV, 256, 0, stream>>>(W1, b1, W2, b2, coef, tks);
  hipMemsetAsync(counts, 0, (size_t)N * 4, stream);
  hist_kernel<<<(E + 255) / 256, 256, 0, stream>>>(dst, counts, E);
  int nb = (N + 1023) / 1024;
  scan1_kernel<<<nb, 1024, 0, stream>>>(counts, offs, bsums, N);
  scan2_kernel<<<1, 64, 0, stream>>>(bsums, nb);
  scan3_kernel<<<(N + 1 + 255) / 256, 256, 0, stream>>>(offs, bsums, cursor, N, E);
  scatter_kernel<<<(E + 255) / 256, 256, 0, stream>>>(pos, src, dst, cursor, esrcS, egeoS, E);

  float sc8 = 1.0f / sqrtf(8.0f);
  float sc32 = 1.0f / sqrtf(32.0f);
  int nblk = (N + ET - 1) / ET;
  pack_kernel<<<nblk, 512, 0, stream>>>(f0, f1, Wq, sc8, fpk, qbuf, N);

  float* out0 = (float*)d_out;
  float* out1 = out0 + (size_t)N * CCH;
  for (int l = 0; l < 5; l++) {
    bool last = (l == 4);
    int ch = last ? 32 : 8;
    node_kernel<<<512, 1024, 0, stream>>>(
        fpk, qbuf, Opk, esrcS, egeoS, offs,
        coef + (size_t)l * NIV * NCH, tks + l * HRAD, ch, N);
    epi_kernel<<<nblk, 512, 0, stream>>>(
        Opk, fpk,
        Wo0 + l * CCH * CCH, Ws0 + l * CCH * CCH,
        Wo1 + l * CCH * CCH, Ws1 + l * CCH * CCH,
        bg + (last ? 0 : l) * CCH,
        Wq + (l + 1 <= 4 ? (l + 1) : 4) * CCH * CCH, qbuf,
        (l + 1 == 4) ? sc32 : sc8,
        out0, out1, last ? 1 : 0, N);
  }
}